// Round 2
// baseline (98.783 us; speedup 1.0000x reference)
//
#include <hip/hip_runtime.h>
#include <hip/hip_bf16.h>

// Problem constants (from reference)
#define N_BITS   1024
#define CHANNELS 16
#define WIDTH    512
#define HEIGHT   512
#define MAPSZ    (WIDTH * HEIGHT)   // 262144, and flat_idx == i since W==H
#define BATCH    32

typedef float f32x4 __attribute__((ext_vector_type(4)));  // native vector: OK for nontemporal builtins

// Each (n,c) plane of 262144 floats is the 1024-float pattern
// (|bits[n,k]|>0.5 ? 1:0) tiled 256 times. Block = 256 threads; each thread
// computes its 4-float pattern chunk once, then streams non-temporal f32x4
// stores at stride N_BITS floats across its segment.

#define SPLIT 4   // segments per (n,c) plane -> grid = 32*16*4 = 2048 blocks

__global__ __launch_bounds__(256) void lte_fill_kernel(
    const float* __restrict__ bits, float* __restrict__ out)
{
    const int tid = threadIdx.x;           // 0..255
    const int blk = blockIdx.x;            // 0..BATCH*CHANNELS*SPLIT-1
    const int seg = blk & (SPLIT - 1);
    const int nc  = blk / SPLIT;
    const int c   = nc & (CHANNELS - 1);
    const int n   = nc / CHANNELS;

    // Pattern chunk for this thread: 4 floats from bits[n, tid*4 .. tid*4+3]
    const f32x4 bv = reinterpret_cast<const f32x4*>(bits + (size_t)n * N_BITS)[tid];
    f32x4 p;
    p.x = (fabsf(bv.x) > 0.5f) ? 1.0f : 0.0f;
    p.y = (fabsf(bv.y) > 0.5f) ? 1.0f : 0.0f;
    p.z = (fabsf(bv.z) > 0.5f) ? 1.0f : 0.0f;
    p.w = (fabsf(bv.w) > 0.5f) ? 1.0f : 0.0f;

    // Destination: start of this segment within the (n,c) plane
    const size_t plane_f4 = MAPSZ / 4;               // 65536 f32x4 per plane
    const size_t seg_f4   = plane_f4 / SPLIT;        // 16384 f32x4 per segment
    f32x4* dst = reinterpret_cast<f32x4*>(out)
               + (size_t)n * (CHANNELS * plane_f4)
               + (size_t)c * plane_f4
               + (size_t)seg * seg_f4
               + tid;

    const int reps   = (int)(seg_f4 / 256);          // 64 iterations
    const int stride = N_BITS / 4;                   // 256 f32x4 = 1024 floats

    #pragma unroll 8
    for (int r = 0; r < reps; ++r) {
        __builtin_nontemporal_store(p, dst + (size_t)r * stride);
    }
}

extern "C" void kernel_launch(void* const* d_in, const int* in_sizes, int n_in,
                              void* d_out, int out_size, void* d_ws, size_t ws_size,
                              hipStream_t stream) {
    const float* bits = (const float*)d_in[0];
    float* out = (float*)d_out;

    const int grid = BATCH * CHANNELS * SPLIT;  // 2048 blocks
    lte_fill_kernel<<<grid, 256, 0, stream>>>(bits, out);
}

// Round 3
// 98.764 us; speedup vs baseline: 1.0002x; 1.0002x over previous
//
#include <hip/hip_runtime.h>
#include <hip/hip_bf16.h>

// Problem constants (from reference)
#define N_BITS   1024
#define CHANNELS 16
#define WIDTH    512
#define HEIGHT   512
#define MAPSZ    (WIDTH * HEIGHT)   // 262144, and flat_idx == i since W==H
#define BATCH    32

typedef float f32x4 __attribute__((ext_vector_type(4)));

// Each (n,c) plane of 262144 floats is the 1024-float pattern
// (|bits[n,k]|>0.5 ? 1:0) tiled 256 times. Block = 256 threads; each thread
// computes its 4-float pattern chunk once, then streams f32x4 stores at
// stride N_BITS floats across its segment. Regular (writeback) stores:
// the harness fill kernel sustains 6.6+ TB/s with them; NT bypass measured
// slower (R2: 5.43 TB/s).

#define SPLIT 8   // segments per (n,c) plane -> grid = 32*16*8 = 4096 blocks

__global__ __launch_bounds__(256) void lte_fill_kernel(
    const float* __restrict__ bits, float* __restrict__ out)
{
    const int tid = threadIdx.x;           // 0..255
    const int blk = blockIdx.x;            // 0..BATCH*CHANNELS*SPLIT-1
    const int seg = blk & (SPLIT - 1);
    const int nc  = blk / SPLIT;
    const int c   = nc & (CHANNELS - 1);
    const int n   = nc / CHANNELS;

    // Pattern chunk for this thread: 4 floats from bits[n, tid*4 .. tid*4+3]
    const f32x4 bv = reinterpret_cast<const f32x4*>(bits + (size_t)n * N_BITS)[tid];
    f32x4 p;
    p.x = (fabsf(bv.x) > 0.5f) ? 1.0f : 0.0f;
    p.y = (fabsf(bv.y) > 0.5f) ? 1.0f : 0.0f;
    p.z = (fabsf(bv.z) > 0.5f) ? 1.0f : 0.0f;
    p.w = (fabsf(bv.w) > 0.5f) ? 1.0f : 0.0f;

    // Destination: start of this segment within the (n,c) plane
    const size_t plane_f4 = MAPSZ / 4;               // 65536 f32x4 per plane
    const size_t seg_f4   = plane_f4 / SPLIT;        // 8192 f32x4 per segment
    f32x4* __restrict__ dst = reinterpret_cast<f32x4*>(out)
               + (size_t)n * (CHANNELS * plane_f4)
               + (size_t)c * plane_f4
               + (size_t)seg * seg_f4
               + tid;

    const int reps   = (int)(seg_f4 / 256);          // 32 iterations
    const int stride = N_BITS / 4;                   // 256 f32x4 = 1024 floats

    #pragma unroll 8
    for (int r = 0; r < reps; ++r) {
        dst[(size_t)r * stride] = p;
    }
}

extern "C" void kernel_launch(void* const* d_in, const int* in_sizes, int n_in,
                              void* d_out, int out_size, void* d_ws, size_t ws_size,
                              hipStream_t stream) {
    const float* bits = (const float*)d_in[0];
    float* out = (float*)d_out;

    const int grid = BATCH * CHANNELS * SPLIT;  // 4096 blocks
    lte_fill_kernel<<<grid, 256, 0, stream>>>(bits, out);
}